// Round 7
// baseline (485.470 us; speedup 1.0000x reference)
//
#include <hip/hip_runtime.h>

// log-ODE Neural CDE. B=32 chains, 32 windows, Heun = 2 vector-field evals
// per window. fp32 in/out, f32 accumulation, f16 weights/activations via
// v_dot2_f32_f16. 1024 threads/block (16 waves, 4/SIMD) for latency hiding;
// one block per batch element. Thread layouts:
//   ph1/2/4/5: (r = t>>3, g = (t>>1)&3 dir-pair, m = t&1 col-half)
//   ph3/6:     (r2 = t>>1 row, hh = t&1 col-half), dir j6 = r2>>6
// Per-thread weight regs: W1 half-row 16 u32, W2 half-row 32, W3 half-row 32
// => ~110 VGPRs, fits the 128 cap at 4 waves/SIMD.
#define NBATCH 32
#define LPATH  513
#define NWIN   32
#define LSIG   36

typedef unsigned int u32;
typedef _Float16 h2 __attribute__((ext_vector_type(2)));

__device__ __forceinline__ u32 pkh(float a, float b){
  return __builtin_bit_cast(u32, __builtin_amdgcn_cvt_pkrtz(a, b));
}
__device__ __forceinline__ float dot2(u32 a, u32 b, float c){
#if __has_builtin(__builtin_amdgcn_fdot2)
  return __builtin_amdgcn_fdot2(__builtin_bit_cast(h2,a),
                                __builtin_bit_cast(h2,b), c, false);
#else
  h2 x = __builtin_bit_cast(h2,a), y = __builtin_bit_cast(h2,b);
  return c + (float)x[0]*(float)y[0] + (float)x[1]*(float)y[1];
#endif
}
__device__ __forceinline__ float tanh_fast(float x){
  float e = __expf(2.f*x);
  return 1.f - 2.f/(e+1.f);
}

extern "C" __global__ __launch_bounds__(1024, 4)
void cde_kernel(const float* __restrict__ cv,
                const float* __restrict__ Wi1g, const float* __restrict__ bi1g,
                const float* __restrict__ Wi2g, const float* __restrict__ bi2g,
                const float* __restrict__ W1g,  const float* __restrict__ b1g,
                const float* __restrict__ W2g,  const float* __restrict__ b2g,
                const float* __restrict__ W3g,  const float* __restrict__ b3g,
                const float* __restrict__ Wrg,  const float* __restrict__ brg,
                const float* __restrict__ shg,
                float* __restrict__ outp)
{
  // ---- LDS (~17 KB) ----
  __shared__ float sG[NWIN*LSIG];
  __shared__ __align__(16) float sF[512];
  __shared__ float sCon[512];
  __shared__ float sB3[512];
  __shared__ float sB1[128], sB2[128];
  __shared__ float sWr[256], sBr[4], sSh[1];
  __shared__ float sC[64];
  __shared__ float sY[64], sK1[64], sK2[64], sLw[64];
  __shared__ __align__(16) _Float16 sYinp[64];
  __shared__ __align__(16) _Float16 sH1[128];
  __shared__ __align__(16) _Float16 sH2[128];
  __shared__ __align__(16) _Float16 sU [8*64];    // [dir][b]
  __shared__ __align__(16) _Float16 sD1[8*128];   // [dir][row]
  __shared__ __align__(16) _Float16 sD2[8*128];   // [dir][row]

  const int t  = threadIdx.x;        // 0..1023
  const int b  = blockIdx.x;
  const int r  = t >> 3;             // 0..127
  const int m  = t & 1;              // col half
  const int d0 = (t >> 1) & 3;       // dir-pair base /2
  const int r2 = t >> 1;             // 0..511
  const int hh = t & 1;
  const int j6 = r2 >> 6;            // dir for ph3/6 row block

  // ---- init biases / readout ----
  if (t < 512) sB3[t] = b3g[t];
  if (t < 128){ sB1[t] = b1g[t]; sB2[t] = b2g[t]; }
  if (t < 256) sWr[t] = Wrg[t];
  if (t < 4)   sBr[t] = brg[t];
  if (t == 0)  sSh[0] = shg[0];

  // ---- depth-2 Lyndon log-signatures, one window per thread (t<32) ----
  if (t < NWIN){
    const float4* cv4 = (const float4*)cv;
    const int base = (b*LPATH + t*16)*2;
    float cur[8], pre[8], acc[8], lv[28];
    { float4 a = cv4[base], d = cv4[base+1];
      cur[0]=a.x;cur[1]=a.y;cur[2]=a.z;cur[3]=a.w;
      cur[4]=d.x;cur[5]=d.y;cur[6]=d.z;cur[7]=d.w; }
    #pragma unroll
    for (int d=0; d<8; d++){ pre[d]=0.f; acc[d]=0.f; }
    #pragma unroll
    for (int p=0; p<28; p++) lv[p]=0.f;
    for (int w=1; w<=16; w++){
      float nxt[8], inc[8];
      { float4 a = cv4[base+2*w], d = cv4[base+2*w+1];
        nxt[0]=a.x;nxt[1]=a.y;nxt[2]=a.z;nxt[3]=a.w;
        nxt[4]=d.x;nxt[5]=d.y;nxt[6]=d.z;nxt[7]=d.w; }
      #pragma unroll
      for (int d=0; d<8; d++) inc[d] = nxt[d]-cur[d];
      int p=0;
      #pragma unroll
      for (int i=0; i<8; i++)
        #pragma unroll
        for (int j2=i+1; j2<8; j2++){ lv[p] += pre[i]*inc[j2] - pre[j2]*inc[i]; p++; }
      #pragma unroll
      for (int d=0; d<8; d++){ acc[d]+=inc[d]; pre[d]+=inc[d]; cur[d]=nxt[d]; }
    }
    float* gd = &sG[t*LSIG];
    #pragma unroll
    for (int d=0; d<8; d++) gd[d] = acc[d];
    #pragma unroll
    for (int p=0; p<28; p++) gd[8+p] = 0.5f*lv[p];
  }

  // ---- y0 = Wi2 @ lipswish(Wi1 @ x0 + bi1) + bi2 ----
  if (t < 64){
    float z = bi1g[t];
    #pragma unroll
    for (int d=0; d<8; d++) z += Wi1g[t*8+d] * cv[(b*LPATH)*8 + d];
    float s = 1.f/(1.f+__expf(-z));
    sLw[t] = 0.909f*z*s;
  }
  __syncthreads();
  if (t < 64){
    float z = bi2g[t];
    #pragma unroll 8
    for (int k=0; k<64; k++) z += Wi2g[t*64+k] * sLw[k];
    sY[t] = z;
    sYinp[t] = (_Float16)z;
  }
  __syncthreads();
  if (t < 4){
    float z = sBr[t] + sSh[0];
    #pragma unroll 8
    for (int a=0; a<64; a++) z += sWr[t*64+a]*sY[a];
    outp[(b*33 + 0)*4 + t] = z;
  }

  // ---- per-thread weight registers (f16 packed), loaded after logsig to
  // keep register live-ranges disjoint ----
  u32 w1[16], w2[32], w3[32];
  {
    const float2* W1f2 = (const float2*)W1g;
    #pragma unroll
    for (int i=0; i<16; i++){ float2 v = W1f2[r*32 + m*16 + i]; w1[i] = pkh(v.x, v.y); }
    const float2* W2f2 = (const float2*)W2g;
    #pragma unroll
    for (int i=0; i<32; i++){ float2 v = W2f2[r*64 + m*32 + i]; w2[i] = pkh(v.x, v.y); }
    const float2* W3f2 = (const float2*)W3g;
    #pragma unroll
    for (int i=0; i<32; i++){ float2 v = W3f2[r2*64 + hh*32 + i]; w3[i] = pkh(v.x, v.y); }
  }

  // One vector-field eval: sYinp -> kout (= M(y) @ logsig; dt cancels)
  auto EVAL = [&](const float* gcur, float* kout){
    __syncthreads();                          // sYinp, sC ready
    float dp1, dp2, fr;
    // ph1: z1 = W1@y + b1. (r,m): 32-col half, 1 shfl.
    {
      const uint4* y4 = (const uint4*)sYinp;
      uint4 a = y4[m*4+0], bb = y4[m*4+1], cc = y4[m*4+2], dd = y4[m*4+3];
      float z = dot2(w1[0], a.x, 0.f);
      z = dot2(w1[1],  a.y, z); z = dot2(w1[2],  a.z, z); z = dot2(w1[3],  a.w, z);
      z = dot2(w1[4],  bb.x, z); z = dot2(w1[5],  bb.y, z); z = dot2(w1[6],  bb.z, z); z = dot2(w1[7],  bb.w, z);
      z = dot2(w1[8],  cc.x, z); z = dot2(w1[9],  cc.y, z); z = dot2(w1[10], cc.z, z); z = dot2(w1[11], cc.w, z);
      z = dot2(w1[12], dd.x, z); z = dot2(w1[13], dd.y, z); z = dot2(w1[14], dd.z, z); z = dot2(w1[15], dd.w, z);
      z += __shfl_xor(z, 1);
      z += sB1[r];
      float s = 1.f/(1.f+__expf(-z));
      dp1 = 0.909f*s*(1.f + z*(1.f-s));
      if ((t & 7) == 0) sH1[r] = (_Float16)(0.909f*z*s);
    }
    __syncthreads();
    // ph2: z2 = W2@h1 + b2. (r,m): 64-col half, 1 shfl.
    {
      const uint4* h4 = (const uint4*)sH1;
      float z = 0.f;
      #pragma unroll
      for (int q=0; q<8; q++){
        uint4 v = h4[m*8 + q];
        z = dot2(w2[4*q+0], v.x, z); z = dot2(w2[4*q+1], v.y, z);
        z = dot2(w2[4*q+2], v.z, z); z = dot2(w2[4*q+3], v.w, z);
      }
      z += __shfl_xor(z, 1);
      z += sB2[r];
      float s = 1.f/(1.f+__expf(-z));
      dp2 = 0.909f*s*(1.f + z*(1.f-s));
      if ((t & 7) == 0) sH2[r] = (_Float16)(0.909f*z*s);
    }
    __syncthreads();
    // ph3: f = tanh(W3@h2 + b3). (r2,hh): 64-col half, 1 shfl.
    {
      const uint4* h4 = (const uint4*)sH2;
      float a0=0.f, a1=0.f;
      #pragma unroll
      for (int q=0; q<8; q++){
        uint4 v = h4[hh*8 + q];
        a0 = dot2(w3[4*q+0], v.x, a0); a1 = dot2(w3[4*q+1], v.y, a1);
        a0 = dot2(w3[4*q+2], v.z, a0); a1 = dot2(w3[4*q+3], v.w, a1);
      }
      float z = a0 + a1;
      z += __shfl_xor(z, 1);
      fr = tanh_fast(z + sB3[r2]);
      if (hh == 0) sF[r2] = fr;
    }
    __syncthreads();
    // U-fold: u_j[b] = sum_i C[j,i] f[i*64+b]; duplicated across wave pairs.
    {
      int jj = (t >> 6) & 7, bb = t & 63;
      float u = 0.f;
      #pragma unroll
      for (int i=0; i<8; i++) u += sC[jj*8 + i] * sF[i*64 + bb];
      sU[jj*64 + bb] = (_Float16)u;          // duplicate write, same value
    }
    __syncthreads();
    // ph4: D1[d] = lipswish'(z1) * (W1 @ u_d). (r, d0 pair, m): no reduce loops.
    {
      const uint4* u4 = (const uint4*)sU;
      float a0=0.f, a1=0.f;
      #pragma unroll
      for (int q=0; q<4; q++){
        uint4 va = u4[(2*d0)*8 + m*4 + q];
        a0 = dot2(w1[4*q+0], va.x, a0); a0 = dot2(w1[4*q+1], va.y, a0);
        a0 = dot2(w1[4*q+2], va.z, a0); a0 = dot2(w1[4*q+3], va.w, a0);
        uint4 vb = u4[(2*d0+1)*8 + m*4 + q];
        a1 = dot2(w1[4*q+0], vb.x, a1); a1 = dot2(w1[4*q+1], vb.y, a1);
        a1 = dot2(w1[4*q+2], vb.z, a1); a1 = dot2(w1[4*q+3], vb.w, a1);
      }
      a0 += __shfl_xor(a0, 1);
      a1 += __shfl_xor(a1, 1);
      if (m == 0){
        sD1[(2*d0)*128   + r] = (_Float16)(dp1*a0);
        sD1[(2*d0+1)*128 + r] = (_Float16)(dp1*a1);
      }
    }
    __syncthreads();
    // ph5: D2[d] = lipswish'(z2) * (W2 @ D1[d]). (r, d0 pair, m).
    {
      const uint4* dd4 = (const uint4*)sD1;
      float a0=0.f, a1=0.f;
      #pragma unroll
      for (int q=0; q<8; q++){
        uint4 va = dd4[(2*d0)*16 + m*8 + q];
        a0 = dot2(w2[4*q+0], va.x, a0); a0 = dot2(w2[4*q+1], va.y, a0);
        a0 = dot2(w2[4*q+2], va.z, a0); a0 = dot2(w2[4*q+3], va.w, a0);
        uint4 vb = dd4[(2*d0+1)*16 + m*8 + q];
        a1 = dot2(w2[4*q+0], vb.x, a1); a1 = dot2(w2[4*q+1], vb.y, a1);
        a1 = dot2(w2[4*q+2], vb.z, a1); a1 = dot2(w2[4*q+3], vb.w, a1);
      }
      a0 += __shfl_xor(a0, 1);
      a1 += __shfl_xor(a1, 1);
      if (m == 0){
        sD2[(2*d0)*128   + r] = (_Float16)(dp2*a0);
        sD2[(2*d0+1)*128 + r] = (_Float16)(dp2*a1);
      }
    }
    __syncthreads();
    // ph6: T3[r2] = W3[r2] . D2[j6]; contribution. (r2,hh), 1 shfl.
    {
      const uint4* dd4 = (const uint4*)sD2;
      float a0=0.f, a1=0.f;
      #pragma unroll
      for (int q=0; q<8; q++){
        uint4 v = dd4[j6*16 + hh*8 + q];
        a0 = dot2(w3[4*q+0], v.x, a0); a1 = dot2(w3[4*q+1], v.y, a1);
        a0 = dot2(w3[4*q+2], v.z, a0); a1 = dot2(w3[4*q+3], v.w, a1);
      }
      float z = a0 + a1;
      z += __shfl_xor(z, 1);
      if (hh == 0) sCon[r2] = gcur[j6]*fr + (1.f - fr*fr)*z;
    }
    __syncthreads();
    // ph7: k[a] = sum_j contrib[j*64+a]
    if (t < 64){
      float k = 0.f;
      #pragma unroll
      for (int j=0; j<8; j++) k += sCon[j*64 + t];
      kout[t] = k;
    }
  };

  // ---- main scan over windows ----
  for (int s = 0; s < NWIN; s++){
    const float* gcur = &sG[s*LSIG];
    if (t < 64){                       // bracket coeff matrix C[j*8+i]
      int j = t >> 3, i = t & 7;
      float v = 0.f;
      if (i < j)      v =  gcur[8 + (7*i - (i*(i-1))/2 + (j-i-1))];
      else if (i > j) v = -gcur[8 + (7*j - (j*(j-1))/2 + (i-j-1))];
      sC[t] = v;
    }
    EVAL(gcur, sK1);
    __syncthreads();
    if (t < 64) sYinp[t] = (_Float16)(sY[t] + sK1[t]);
    EVAL(gcur, sK2);
    __syncthreads();
    if (t < 64){
      float yn = sY[t] + 0.5f*(sK1[t] + sK2[t]);
      sY[t] = yn;
      sYinp[t] = (_Float16)yn;
    }
    __syncthreads();
    if (t < 4){
      float z = sBr[t] + sSh[0];
      #pragma unroll 8
      for (int a=0; a<64; a++) z += sWr[t*64+a]*sY[a];
      outp[(b*33 + s + 1)*4 + t] = z;
    }
  }
}

extern "C" void kernel_launch(void* const* d_in, const int* in_sizes, int n_in,
                              void* d_out, int out_size, void* d_ws, size_t ws_size,
                              hipStream_t stream) {
  cde_kernel<<<dim3(NBATCH), dim3(1024), 0, stream>>>(
      (const float*)d_in[0],
      (const float*)d_in[1],  (const float*)d_in[2],
      (const float*)d_in[3],  (const float*)d_in[4],
      (const float*)d_in[5],  (const float*)d_in[6],
      (const float*)d_in[7],  (const float*)d_in[8],
      (const float*)d_in[9],  (const float*)d_in[10],
      (const float*)d_in[11], (const float*)d_in[12],
      (const float*)d_in[13],
      (float*)d_out);
}

// Round 8
// 408.614 us; speedup vs baseline: 1.1881x; 1.1881x over previous
//
#include <hip/hip_runtime.h>

// log-ODE Neural CDE. B=32 chains, 32 windows, Heun = 2 vector-field evals
// per window. fp32 in/out, f32 accumulation, f16 weights/activations via
// v_dot2_f32_f16. 1024 threads/block (16 waves, 4/SIMD); one block per batch
// element. __launch_bounds__(1024, 1): second arg behaves as BLOCKS/CU
// (evidence R4/R6/R7: (256,1)->216, (512,2)->128, (1024,4)->64 VGPRs), so
// (1024,1) = 16 waves/CU = 4/SIMD = 128-VGPR cap; weights need ~80 u32.
#define NBATCH 32
#define LPATH  513
#define NWIN   32
#define LSIG   36
#define DSTR   136   // padded [dir] stride for sD1/sD2 (f16 units): 17 uint4

typedef unsigned int u32;
typedef _Float16 h2 __attribute__((ext_vector_type(2)));

__device__ __forceinline__ u32 pkh(float a, float b){
  return __builtin_bit_cast(u32, __builtin_amdgcn_cvt_pkrtz(a, b));
}
__device__ __forceinline__ float dot2(u32 a, u32 b, float c){
#if __has_builtin(__builtin_amdgcn_fdot2)
  return __builtin_amdgcn_fdot2(__builtin_bit_cast(h2,a),
                                __builtin_bit_cast(h2,b), c, false);
#else
  h2 x = __builtin_bit_cast(h2,a), y = __builtin_bit_cast(h2,b);
  return c + (float)x[0]*(float)y[0] + (float)x[1]*(float)y[1];
#endif
}
__device__ __forceinline__ float tanh_fast(float x){
  float e = __expf(2.f*x);
  return 1.f - 2.f/(e+1.f);
}

extern "C" __global__ __launch_bounds__(1024, 1)
void cde_kernel(const float* __restrict__ cv,
                const float* __restrict__ Wi1g, const float* __restrict__ bi1g,
                const float* __restrict__ Wi2g, const float* __restrict__ bi2g,
                const float* __restrict__ W1g,  const float* __restrict__ b1g,
                const float* __restrict__ W2g,  const float* __restrict__ b2g,
                const float* __restrict__ W3g,  const float* __restrict__ b3g,
                const float* __restrict__ Wrg,  const float* __restrict__ brg,
                const float* __restrict__ shg,
                float* __restrict__ outp)
{
  // ---- LDS (~17 KB) ----
  __shared__ float sG[NWIN*LSIG];
  __shared__ __align__(16) float sF[512];
  __shared__ float sCon[512];
  __shared__ float sB3[512];
  __shared__ float sB1[128], sB2[128];
  __shared__ float sWr[256], sBr[4], sSh[1];
  __shared__ float sC[64];
  __shared__ float sY[64], sK1[64], sK2[64], sLw[64];
  __shared__ __align__(16) _Float16 sYinp[64];
  __shared__ __align__(16) _Float16 sH1[128];
  __shared__ __align__(16) _Float16 sH2[128];
  __shared__ __align__(16) _Float16 sU [8*64];       // [dir][b]
  __shared__ __align__(16) _Float16 sD1[8*DSTR];     // [dir][row], padded
  __shared__ __align__(16) _Float16 sD2[8*DSTR];     // [dir][row], padded

  const int t  = threadIdx.x;        // 0..1023
  const int b  = blockIdx.x;
  const int r  = t >> 3;             // 0..127
  const int m  = t & 1;              // col half
  const int d0 = (t >> 1) & 3;       // dir-pair index
  const int r2 = t >> 1;             // 0..511
  const int hh = t & 1;
  const int j6 = r2 >> 6;            // dir for ph3/6 row block

  // ---- init biases / readout ----
  if (t < 512) sB3[t] = b3g[t];
  if (t < 128){ sB1[t] = b1g[t]; sB2[t] = b2g[t]; }
  if (t < 256) sWr[t] = Wrg[t];
  if (t < 4)   sBr[t] = brg[t];
  if (t == 0)  sSh[0] = shg[0];

  // ---- depth-2 Lyndon log-signatures, one window per thread (t<32) ----
  if (t < NWIN){
    const float4* cv4 = (const float4*)cv;
    const int base = (b*LPATH + t*16)*2;
    float cur[8], pre[8], acc[8], lv[28];
    { float4 a = cv4[base], d = cv4[base+1];
      cur[0]=a.x;cur[1]=a.y;cur[2]=a.z;cur[3]=a.w;
      cur[4]=d.x;cur[5]=d.y;cur[6]=d.z;cur[7]=d.w; }
    #pragma unroll
    for (int d=0; d<8; d++){ pre[d]=0.f; acc[d]=0.f; }
    #pragma unroll
    for (int p=0; p<28; p++) lv[p]=0.f;
    for (int w=1; w<=16; w++){
      float nxt[8], inc[8];
      { float4 a = cv4[base+2*w], d = cv4[base+2*w+1];
        nxt[0]=a.x;nxt[1]=a.y;nxt[2]=a.z;nxt[3]=a.w;
        nxt[4]=d.x;nxt[5]=d.y;nxt[6]=d.z;nxt[7]=d.w; }
      #pragma unroll
      for (int d=0; d<8; d++) inc[d] = nxt[d]-cur[d];
      int p=0;
      #pragma unroll
      for (int i=0; i<8; i++)
        #pragma unroll
        for (int j2=i+1; j2<8; j2++){ lv[p] += pre[i]*inc[j2] - pre[j2]*inc[i]; p++; }
      #pragma unroll
      for (int d=0; d<8; d++){ acc[d]+=inc[d]; pre[d]+=inc[d]; cur[d]=nxt[d]; }
    }
    float* gd = &sG[t*LSIG];
    #pragma unroll
    for (int d=0; d<8; d++) gd[d] = acc[d];
    #pragma unroll
    for (int p=0; p<28; p++) gd[8+p] = 0.5f*lv[p];
  }

  // ---- y0 = Wi2 @ lipswish(Wi1 @ x0 + bi1) + bi2 ----
  if (t < 64){
    float z = bi1g[t];
    #pragma unroll
    for (int d=0; d<8; d++) z += Wi1g[t*8+d] * cv[(b*LPATH)*8 + d];
    float s = 1.f/(1.f+__expf(-z));
    sLw[t] = 0.909f*z*s;
  }
  __syncthreads();
  if (t < 64){
    float z = bi2g[t];
    #pragma unroll 8
    for (int k=0; k<64; k++) z += Wi2g[t*64+k] * sLw[k];
    sY[t] = z;
    sYinp[t] = (_Float16)z;
  }
  __syncthreads();
  if (t < 4){
    float z = sBr[t] + sSh[0];
    #pragma unroll 8
    for (int a=0; a<64; a++) z += sWr[t*64+a]*sY[a];
    outp[(b*33 + 0)*4 + t] = z;
  }

  // ---- per-thread weight registers (f16 packed): 16+32+32 = 80 u32 ----
  u32 w1[16], w2[32], w3[32];
  {
    const float2* W1f2 = (const float2*)W1g;
    #pragma unroll
    for (int i=0; i<16; i++){ float2 v = W1f2[r*32 + m*16 + i]; w1[i] = pkh(v.x, v.y); }
    const float2* W2f2 = (const float2*)W2g;
    #pragma unroll
    for (int i=0; i<32; i++){ float2 v = W2f2[r*64 + m*32 + i]; w2[i] = pkh(v.x, v.y); }
    const float2* W3f2 = (const float2*)W3g;
    #pragma unroll
    for (int i=0; i<32; i++){ float2 v = W3f2[r2*64 + hh*32 + i]; w3[i] = pkh(v.x, v.y); }
  }

  // One vector-field eval: sYinp -> kout (= M(y) @ logsig; dt cancels)
  auto EVAL = [&](const float* gcur, float* kout){
    __syncthreads();                          // sYinp, sC ready
    float dp1, dp2, fr;
    // ph1: z1 = W1@y + b1. (r,m): 32-col half, 2 acc chains, 1 shfl.
    {
      const uint4* y4 = (const uint4*)sYinp;
      uint4 a = y4[m*4+0], bb = y4[m*4+1], cc = y4[m*4+2], dd = y4[m*4+3];
      float z0 = dot2(w1[0], a.x, 0.f), z1 = dot2(w1[1], a.y, 0.f);
      z0 = dot2(w1[2],  a.z, z0);  z1 = dot2(w1[3],  a.w, z1);
      z0 = dot2(w1[4],  bb.x, z0); z1 = dot2(w1[5],  bb.y, z1);
      z0 = dot2(w1[6],  bb.z, z0); z1 = dot2(w1[7],  bb.w, z1);
      z0 = dot2(w1[8],  cc.x, z0); z1 = dot2(w1[9],  cc.y, z1);
      z0 = dot2(w1[10], cc.z, z0); z1 = dot2(w1[11], cc.w, z1);
      z0 = dot2(w1[12], dd.x, z0); z1 = dot2(w1[13], dd.y, z1);
      z0 = dot2(w1[14], dd.z, z0); z1 = dot2(w1[15], dd.w, z1);
      float z = z0 + z1;
      z += __shfl_xor(z, 1);
      z += sB1[r];
      float s = 1.f/(1.f+__expf(-z));
      dp1 = 0.909f*s*(1.f + z*(1.f-s));
      if ((t & 7) == 0) sH1[r] = (_Float16)(0.909f*z*s);
    }
    __syncthreads();
    // ph2: z2 = W2@h1 + b2. (r,m): 64-col half, 2 acc chains, 1 shfl.
    {
      const uint4* h4 = (const uint4*)sH1;
      float z0 = 0.f, z1 = 0.f;
      #pragma unroll
      for (int q=0; q<8; q++){
        uint4 v = h4[m*8 + q];
        z0 = dot2(w2[4*q+0], v.x, z0); z1 = dot2(w2[4*q+1], v.y, z1);
        z0 = dot2(w2[4*q+2], v.z, z0); z1 = dot2(w2[4*q+3], v.w, z1);
      }
      float z = z0 + z1;
      z += __shfl_xor(z, 1);
      z += sB2[r];
      float s = 1.f/(1.f+__expf(-z));
      dp2 = 0.909f*s*(1.f + z*(1.f-s));
      if ((t & 7) == 0) sH2[r] = (_Float16)(0.909f*z*s);
    }
    __syncthreads();
    // ph3: f = tanh(W3@h2 + b3). (r2,hh): 64-col half, 1 shfl.
    {
      const uint4* h4 = (const uint4*)sH2;
      float a0=0.f, a1=0.f;
      #pragma unroll
      for (int q=0; q<8; q++){
        uint4 v = h4[hh*8 + q];
        a0 = dot2(w3[4*q+0], v.x, a0); a1 = dot2(w3[4*q+1], v.y, a1);
        a0 = dot2(w3[4*q+2], v.z, a0); a1 = dot2(w3[4*q+3], v.w, a1);
      }
      float z = a0 + a1;
      z += __shfl_xor(z, 1);
      fr = tanh_fast(z + sB3[r2]);
      if (hh == 0) sF[r2] = fr;
    }
    __syncthreads();
    // U-fold: u_j[b] = sum_i C[j,i] f[i*64+b]; duplicated across wave pairs.
    {
      int jj = (t >> 6) & 7, bb = t & 63;
      float u = 0.f;
      #pragma unroll
      for (int i=0; i<8; i++) u += sC[jj*8 + i] * sF[i*64 + bb];
      sU[jj*64 + bb] = (_Float16)u;          // duplicate write, same value
    }
    __syncthreads();
    // ph4: D1[d] = lipswish'(z1) * (W1 @ u_d). (r, d0 pair, m).
    {
      const uint4* u4 = (const uint4*)sU;
      float a0=0.f, a1=0.f;
      #pragma unroll
      for (int q=0; q<4; q++){
        uint4 va = u4[(2*d0)*8 + m*4 + q];
        a0 = dot2(w1[4*q+0], va.x, a0); a0 = dot2(w1[4*q+1], va.y, a0);
        a0 = dot2(w1[4*q+2], va.z, a0); a0 = dot2(w1[4*q+3], va.w, a0);
        uint4 vb = u4[(2*d0+1)*8 + m*4 + q];
        a1 = dot2(w1[4*q+0], vb.x, a1); a1 = dot2(w1[4*q+1], vb.y, a1);
        a1 = dot2(w1[4*q+2], vb.z, a1); a1 = dot2(w1[4*q+3], vb.w, a1);
      }
      a0 += __shfl_xor(a0, 1);
      a1 += __shfl_xor(a1, 1);
      if (m == 0){
        sD1[(2*d0)*DSTR   + r] = (_Float16)(dp1*a0);
        sD1[(2*d0+1)*DSTR + r] = (_Float16)(dp1*a1);
      }
    }
    __syncthreads();
    // ph5: D2[d] = lipswish'(z2) * (W2 @ D1[d]). (r, d0 pair, m).
    {
      const uint4* dd4 = (const uint4*)sD1;
      float a0=0.f, a1=0.f;
      #pragma unroll
      for (int q=0; q<8; q++){
        uint4 va = dd4[(2*d0)*17 + m*8 + q];
        a0 = dot2(w2[4*q+0], va.x, a0); a0 = dot2(w2[4*q+1], va.y, a0);
        a0 = dot2(w2[4*q+2], va.z, a0); a0 = dot2(w2[4*q+3], va.w, a0);
        uint4 vb = dd4[(2*d0+1)*17 + m*8 + q];
        a1 = dot2(w2[4*q+0], vb.x, a1); a1 = dot2(w2[4*q+1], vb.y, a1);
        a1 = dot2(w2[4*q+2], vb.z, a1); a1 = dot2(w2[4*q+3], vb.w, a1);
      }
      a0 += __shfl_xor(a0, 1);
      a1 += __shfl_xor(a1, 1);
      if (m == 0){
        sD2[(2*d0)*DSTR   + r] = (_Float16)(dp2*a0);
        sD2[(2*d0+1)*DSTR + r] = (_Float16)(dp2*a1);
      }
    }
    __syncthreads();
    // ph6: T3[r2] = W3[r2] . D2[j6]; contribution. (r2,hh), 1 shfl.
    {
      const uint4* dd4 = (const uint4*)sD2;
      float a0=0.f, a1=0.f;
      #pragma unroll
      for (int q=0; q<8; q++){
        uint4 v = dd4[j6*17 + hh*8 + q];
        a0 = dot2(w3[4*q+0], v.x, a0); a1 = dot2(w3[4*q+1], v.y, a1);
        a0 = dot2(w3[4*q+2], v.z, a0); a1 = dot2(w3[4*q+3], v.w, a1);
      }
      float z = a0 + a1;
      z += __shfl_xor(z, 1);
      if (hh == 0) sCon[r2] = gcur[j6]*fr + (1.f - fr*fr)*z;
    }
    __syncthreads();
    // ph7: k[a] = sum_j contrib[j*64+a]
    if (t < 64){
      float k = 0.f;
      #pragma unroll
      for (int j=0; j<8; j++) k += sCon[j*64 + t];
      kout[t] = k;
    }
  };

  // ---- main scan over windows ----
  for (int s = 0; s < NWIN; s++){
    const float* gcur = &sG[s*LSIG];
    if (t < 64){                       // bracket coeff matrix C[j*8+i]
      int j = t >> 3, i = t & 7;
      float v = 0.f;
      if (i < j)      v =  gcur[8 + (7*i - (i*(i-1))/2 + (j-i-1))];
      else if (i > j) v = -gcur[8 + (7*j - (j*(j-1))/2 + (i-j-1))];
      sC[t] = v;
    }
    EVAL(gcur, sK1);
    __syncthreads();
    if (t < 64) sYinp[t] = (_Float16)(sY[t] + sK1[t]);
    EVAL(gcur, sK2);
    __syncthreads();
    if (t < 64){
      float yn = sY[t] + 0.5f*(sK1[t] + sK2[t]);
      sY[t] = yn;
      sYinp[t] = (_Float16)yn;
    }
    __syncthreads();
    if (t < 4){
      float z = sBr[t] + sSh[0];
      #pragma unroll 8
      for (int a=0; a<64; a++) z += sWr[t*64+a]*sY[a];
      outp[(b*33 + s + 1)*4 + t] = z;
    }
  }
}

extern "C" void kernel_launch(void* const* d_in, const int* in_sizes, int n_in,
                              void* d_out, int out_size, void* d_ws, size_t ws_size,
                              hipStream_t stream) {
  cde_kernel<<<dim3(NBATCH), dim3(1024), 0, stream>>>(
      (const float*)d_in[0],
      (const float*)d_in[1],  (const float*)d_in[2],
      (const float*)d_in[3],  (const float*)d_in[4],
      (const float*)d_in[5],  (const float*)d_in[6],
      (const float*)d_in[7],  (const float*)d_in[8],
      (const float*)d_in[9],  (const float*)d_in[10],
      (const float*)d_in[11], (const float*)d_in[12],
      (const float*)d_in[13],
      (float*)d_out);
}

// Round 9
// 380.936 us; speedup vs baseline: 1.2744x; 1.0727x over previous
//
#include <hip/hip_runtime.h>

// log-ODE Neural CDE. B=32 chains, 32 windows, Heun = 2 vector-field evals
// per window. fp32 in/out, f32 accumulation, f16 weights/activations via
// v_dot2_f32_f16. 1024 threads/block (16 waves, 4/SIMD); one block per batch
// element. amdgpu_waves_per_eu(4,4) pins occupancy to exactly 4 waves/EU =>
// 128-VGPR budget (launch_bounds' 2nd arg is only a MIN — R7/R8 showed the
// compiler still targets 8/EU = 64 VGPRs and spills the 80 weight regs).
#define NBATCH 32
#define LPATH  513
#define NWIN   32
#define LSIG   36
#define DSTR   136   // [dir] stride for sD1/sD2 in f16 (17 uint4) - conflict-free
#define USTR   72    // [dir] stride for sU in f16 (9 uint4) - spreads bank quads

typedef unsigned int u32;
typedef _Float16 h2 __attribute__((ext_vector_type(2)));

__device__ __forceinline__ u32 pkh(float a, float b){
  return __builtin_bit_cast(u32, __builtin_amdgcn_cvt_pkrtz(a, b));
}
__device__ __forceinline__ float dot2(u32 a, u32 b, float c){
#if __has_builtin(__builtin_amdgcn_fdot2)
  return __builtin_amdgcn_fdot2(__builtin_bit_cast(h2,a),
                                __builtin_bit_cast(h2,b), c, false);
#else
  h2 x = __builtin_bit_cast(h2,a), y = __builtin_bit_cast(h2,b);
  return c + (float)x[0]*(float)y[0] + (float)x[1]*(float)y[1];
#endif
}
__device__ __forceinline__ float tanh_fast(float x){
  float e = __expf(2.f*x);
  return 1.f - 2.f/(e+1.f);
}

extern "C" __global__
__attribute__((amdgpu_flat_work_group_size(1024, 1024), amdgpu_waves_per_eu(4, 4)))
void cde_kernel(const float* __restrict__ cv,
                const float* __restrict__ Wi1g, const float* __restrict__ bi1g,
                const float* __restrict__ Wi2g, const float* __restrict__ bi2g,
                const float* __restrict__ W1g,  const float* __restrict__ b1g,
                const float* __restrict__ W2g,  const float* __restrict__ b2g,
                const float* __restrict__ W3g,  const float* __restrict__ b3g,
                const float* __restrict__ Wrg,  const float* __restrict__ brg,
                const float* __restrict__ shg,
                float* __restrict__ outp)
{
  // ---- LDS (~17 KB) ----
  __shared__ float sG[NWIN*LSIG];
  __shared__ __align__(16) float sF[512];
  __shared__ float sCon[512];
  __shared__ float sB3[512];
  __shared__ float sB1[128], sB2[128];
  __shared__ float sWr[256], sBr[4], sSh[1];
  __shared__ float sC[64];
  __shared__ float sY[64], sK1[64], sK2[64], sLw[64];
  __shared__ __align__(16) _Float16 sYinp[64];
  __shared__ __align__(16) _Float16 sH1[128];
  __shared__ __align__(16) _Float16 sH2[128];
  __shared__ __align__(16) _Float16 sU [8*USTR];     // [dir][b], padded
  __shared__ __align__(16) _Float16 sD1[8*DSTR];     // [dir][row], padded
  __shared__ __align__(16) _Float16 sD2[8*DSTR];     // [dir][row], padded

  const int t  = threadIdx.x;        // 0..1023
  const int b  = blockIdx.x;
  const int r  = t >> 3;             // 0..127
  const int m  = t & 1;              // col half
  const int d0 = (t >> 1) & 3;       // dir-pair index
  const int r2 = t >> 1;             // 0..511
  const int hh = t & 1;
  const int j6 = r2 >> 6;            // dir for ph3/6 row block

  // ---- init biases / readout ----
  if (t < 512) sB3[t] = b3g[t];
  if (t < 128){ sB1[t] = b1g[t]; sB2[t] = b2g[t]; }
  if (t < 256) sWr[t] = Wrg[t];
  if (t < 4)   sBr[t] = brg[t];
  if (t == 0)  sSh[0] = shg[0];

  // ---- depth-2 Lyndon log-signatures, one window per thread (t<32) ----
  if (t < NWIN){
    const float4* cv4 = (const float4*)cv;
    const int base = (b*LPATH + t*16)*2;
    float cur[8], pre[8], acc[8], lv[28];
    { float4 a = cv4[base], d = cv4[base+1];
      cur[0]=a.x;cur[1]=a.y;cur[2]=a.z;cur[3]=a.w;
      cur[4]=d.x;cur[5]=d.y;cur[6]=d.z;cur[7]=d.w; }
    #pragma unroll
    for (int d=0; d<8; d++){ pre[d]=0.f; acc[d]=0.f; }
    #pragma unroll
    for (int p=0; p<28; p++) lv[p]=0.f;
    for (int w=1; w<=16; w++){
      float nxt[8], inc[8];
      { float4 a = cv4[base+2*w], d = cv4[base+2*w+1];
        nxt[0]=a.x;nxt[1]=a.y;nxt[2]=a.z;nxt[3]=a.w;
        nxt[4]=d.x;nxt[5]=d.y;nxt[6]=d.z;nxt[7]=d.w; }
      #pragma unroll
      for (int d=0; d<8; d++) inc[d] = nxt[d]-cur[d];
      int p=0;
      #pragma unroll
      for (int i=0; i<8; i++)
        #pragma unroll
        for (int j2=i+1; j2<8; j2++){ lv[p] += pre[i]*inc[j2] - pre[j2]*inc[i]; p++; }
      #pragma unroll
      for (int d=0; d<8; d++){ acc[d]+=inc[d]; pre[d]+=inc[d]; cur[d]=nxt[d]; }
    }
    float* gd = &sG[t*LSIG];
    #pragma unroll
    for (int d=0; d<8; d++) gd[d] = acc[d];
    #pragma unroll
    for (int p=0; p<28; p++) gd[8+p] = 0.5f*lv[p];
  }

  // ---- y0 = Wi2 @ lipswish(Wi1 @ x0 + bi1) + bi2 ----
  if (t < 64){
    float z = bi1g[t];
    #pragma unroll
    for (int d=0; d<8; d++) z += Wi1g[t*8+d] * cv[(b*LPATH)*8 + d];
    float s = 1.f/(1.f+__expf(-z));
    sLw[t] = 0.909f*z*s;
  }
  __syncthreads();
  if (t < 64){
    float z = bi2g[t];
    #pragma unroll 8
    for (int k=0; k<64; k++) z += Wi2g[t*64+k] * sLw[k];
    sY[t] = z;
    sYinp[t] = (_Float16)z;
  }
  __syncthreads();
  if (t < 4){
    float z = sBr[t] + sSh[0];
    #pragma unroll 8
    for (int a=0; a<64; a++) z += sWr[t*64+a]*sY[a];
    outp[(b*33 + 0)*4 + t] = z;
  }

  // ---- per-thread weight registers (f16 packed): 16+32+32 = 80 u32 ----
  u32 w1[16], w2[32], w3[32];
  {
    const float2* W1f2 = (const float2*)W1g;
    #pragma unroll
    for (int i=0; i<16; i++){ float2 v = W1f2[r*32 + m*16 + i]; w1[i] = pkh(v.x, v.y); }
    const float2* W2f2 = (const float2*)W2g;
    #pragma unroll
    for (int i=0; i<32; i++){ float2 v = W2f2[r*64 + m*32 + i]; w2[i] = pkh(v.x, v.y); }
    const float2* W3f2 = (const float2*)W3g;
    #pragma unroll
    for (int i=0; i<32; i++){ float2 v = W3f2[r2*64 + hh*32 + i]; w3[i] = pkh(v.x, v.y); }
  }

  // One vector-field eval: sYinp -> kout (= M(y) @ logsig; dt cancels)
  auto EVAL = [&](const float* gcur, float* kout){
    __syncthreads();                          // sYinp, sC ready
    float dp1, dp2, fr;
    // ph1: z1 = W1@y + b1. (r,m): 32-col half, 2 acc chains, 1 shfl.
    {
      const uint4* y4 = (const uint4*)sYinp;
      uint4 a = y4[m*4+0], bb = y4[m*4+1], cc = y4[m*4+2], dd = y4[m*4+3];
      float z0 = dot2(w1[0], a.x, 0.f), z1 = dot2(w1[1], a.y, 0.f);
      z0 = dot2(w1[2],  a.z, z0);  z1 = dot2(w1[3],  a.w, z1);
      z0 = dot2(w1[4],  bb.x, z0); z1 = dot2(w1[5],  bb.y, z1);
      z0 = dot2(w1[6],  bb.z, z0); z1 = dot2(w1[7],  bb.w, z1);
      z0 = dot2(w1[8],  cc.x, z0); z1 = dot2(w1[9],  cc.y, z1);
      z0 = dot2(w1[10], cc.z, z0); z1 = dot2(w1[11], cc.w, z1);
      z0 = dot2(w1[12], dd.x, z0); z1 = dot2(w1[13], dd.y, z1);
      z0 = dot2(w1[14], dd.z, z0); z1 = dot2(w1[15], dd.w, z1);
      float z = z0 + z1;
      z += __shfl_xor(z, 1);
      z += sB1[r];
      float s = 1.f/(1.f+__expf(-z));
      dp1 = 0.909f*s*(1.f + z*(1.f-s));
      if ((t & 7) == 0) sH1[r] = (_Float16)(0.909f*z*s);
    }
    __syncthreads();
    // ph2: z2 = W2@h1 + b2. (r,m): 64-col half, 2 acc chains, 1 shfl.
    {
      const uint4* h4 = (const uint4*)sH1;
      float z0 = 0.f, z1 = 0.f;
      #pragma unroll
      for (int q=0; q<8; q++){
        uint4 v = h4[m*8 + q];
        z0 = dot2(w2[4*q+0], v.x, z0); z1 = dot2(w2[4*q+1], v.y, z1);
        z0 = dot2(w2[4*q+2], v.z, z0); z1 = dot2(w2[4*q+3], v.w, z1);
      }
      float z = z0 + z1;
      z += __shfl_xor(z, 1);
      z += sB2[r];
      float s = 1.f/(1.f+__expf(-z));
      dp2 = 0.909f*s*(1.f + z*(1.f-s));
      if ((t & 7) == 0) sH2[r] = (_Float16)(0.909f*z*s);
    }
    __syncthreads();
    // ph3: f = tanh(W3@h2 + b3). (r2,hh): 64-col half, 1 shfl.
    {
      const uint4* h4 = (const uint4*)sH2;
      float a0=0.f, a1=0.f;
      #pragma unroll
      for (int q=0; q<8; q++){
        uint4 v = h4[hh*8 + q];
        a0 = dot2(w3[4*q+0], v.x, a0); a1 = dot2(w3[4*q+1], v.y, a1);
        a0 = dot2(w3[4*q+2], v.z, a0); a1 = dot2(w3[4*q+3], v.w, a1);
      }
      float z = a0 + a1;
      z += __shfl_xor(z, 1);
      fr = tanh_fast(z + sB3[r2]);
      if (hh == 0) sF[r2] = fr;
    }
    __syncthreads();
    // U-fold: u_j[b] = sum_i C[j,i] f[i*64+b]; duplicated across halves.
    {
      int jj = (t >> 6) & 7, bb = t & 63;
      float u = 0.f;
      #pragma unroll
      for (int i=0; i<8; i++) u += sC[jj*8 + i] * sF[i*64 + bb];
      sU[jj*USTR + bb] = (_Float16)u;        // duplicate write, same value
    }
    __syncthreads();
    // ph4: D1[d] = lipswish'(z1) * (W1 @ u_d). (r, d0 pair, m).
    {
      const uint4* u4 = (const uint4*)sU;    // dir stride 9 uint4
      float a0=0.f, a1=0.f;
      #pragma unroll
      for (int q=0; q<4; q++){
        uint4 va = u4[(2*d0)*9 + m*4 + q];
        a0 = dot2(w1[4*q+0], va.x, a0); a0 = dot2(w1[4*q+1], va.y, a0);
        a0 = dot2(w1[4*q+2], va.z, a0); a0 = dot2(w1[4*q+3], va.w, a0);
        uint4 vb = u4[(2*d0+1)*9 + m*4 + q];
        a1 = dot2(w1[4*q+0], vb.x, a1); a1 = dot2(w1[4*q+1], vb.y, a1);
        a1 = dot2(w1[4*q+2], vb.z, a1); a1 = dot2(w1[4*q+3], vb.w, a1);
      }
      a0 += __shfl_xor(a0, 1);
      a1 += __shfl_xor(a1, 1);
      if (m == 0){
        sD1[(2*d0)*DSTR   + r] = (_Float16)(dp1*a0);
        sD1[(2*d0+1)*DSTR + r] = (_Float16)(dp1*a1);
      }
    }
    __syncthreads();
    // ph5: D2[d] = lipswish'(z2) * (W2 @ D1[d]). (r, d0 pair, m).
    {
      const uint4* dd4 = (const uint4*)sD1;  // dir stride 17 uint4
      float a0=0.f, a1=0.f;
      #pragma unroll
      for (int q=0; q<8; q++){
        uint4 va = dd4[(2*d0)*17 + m*8 + q];
        a0 = dot2(w2[4*q+0], va.x, a0); a0 = dot2(w2[4*q+1], va.y, a0);
        a0 = dot2(w2[4*q+2], va.z, a0); a0 = dot2(w2[4*q+3], va.w, a0);
        uint4 vb = dd4[(2*d0+1)*17 + m*8 + q];
        a1 = dot2(w2[4*q+0], vb.x, a1); a1 = dot2(w2[4*q+1], vb.y, a1);
        a1 = dot2(w2[4*q+2], vb.z, a1); a1 = dot2(w2[4*q+3], vb.w, a1);
      }
      a0 += __shfl_xor(a0, 1);
      a1 += __shfl_xor(a1, 1);
      if (m == 0){
        sD2[(2*d0)*DSTR   + r] = (_Float16)(dp2*a0);
        sD2[(2*d0+1)*DSTR + r] = (_Float16)(dp2*a1);
      }
    }
    __syncthreads();
    // ph6: T3[r2] = W3[r2] . D2[j6]; contribution. (r2,hh), 1 shfl.
    {
      const uint4* dd4 = (const uint4*)sD2;
      float a0=0.f, a1=0.f;
      #pragma unroll
      for (int q=0; q<8; q++){
        uint4 v = dd4[j6*17 + hh*8 + q];
        a0 = dot2(w3[4*q+0], v.x, a0); a1 = dot2(w3[4*q+1], v.y, a1);
        a0 = dot2(w3[4*q+2], v.z, a0); a1 = dot2(w3[4*q+3], v.w, a1);
      }
      float z = a0 + a1;
      z += __shfl_xor(z, 1);
      if (hh == 0) sCon[r2] = gcur[j6]*fr + (1.f - fr*fr)*z;
    }
    __syncthreads();
    // ph7: k[a] = sum_j contrib[j*64+a]
    if (t < 64){
      float k = 0.f;
      #pragma unroll
      for (int j=0; j<8; j++) k += sCon[j*64 + t];
      kout[t] = k;
    }
  };

  // ---- main scan over windows ----
  for (int s = 0; s < NWIN; s++){
    const float* gcur = &sG[s*LSIG];
    if (t < 64){                       // bracket coeff matrix C[j*8+i]
      int j = t >> 3, i = t & 7;
      float v = 0.f;
      if (i < j)      v =  gcur[8 + (7*i - (i*(i-1))/2 + (j-i-1))];
      else if (i > j) v = -gcur[8 + (7*j - (j*(j-1))/2 + (i-j-1))];
      sC[t] = v;
    }
    EVAL(gcur, sK1);
    __syncthreads();
    if (t < 64) sYinp[t] = (_Float16)(sY[t] + sK1[t]);
    EVAL(gcur, sK2);
    __syncthreads();
    if (t < 64){
      float yn = sY[t] + 0.5f*(sK1[t] + sK2[t]);
      sY[t] = yn;
      sYinp[t] = (_Float16)yn;
    }
    __syncthreads();
    if (t < 4){
      float z = sBr[t] + sSh[0];
      #pragma unroll 8
      for (int a=0; a<64; a++) z += sWr[t*64+a]*sY[a];
      outp[(b*33 + s + 1)*4 + t] = z;
    }
  }
}

extern "C" void kernel_launch(void* const* d_in, const int* in_sizes, int n_in,
                              void* d_out, int out_size, void* d_ws, size_t ws_size,
                              hipStream_t stream) {
  cde_kernel<<<dim3(NBATCH), dim3(1024), 0, stream>>>(
      (const float*)d_in[0],
      (const float*)d_in[1],  (const float*)d_in[2],
      (const float*)d_in[3],  (const float*)d_in[4],
      (const float*)d_in[5],  (const float*)d_in[6],
      (const float*)d_in[7],  (const float*)d_in[8],
      (const float*)d_in[9],  (const float*)d_in[10],
      (const float*)d_in[11], (const float*)d_in[12],
      (const float*)d_in[13],
      (float*)d_out);
}

// Round 10
// 330.972 us; speedup vs baseline: 1.4668x; 1.1510x over previous
//
#include <hip/hip_runtime.h>

// log-ODE Neural CDE. B=32 chains, 32 windows, Heun = 2 vector-field evals
// per window. fp32 in/out, f32 accum, f16 weights/activations (v_dot2_f32_f16).
// 512 threads/block (8 waves, 2/SIMD), one block per batch element.
// __launch_bounds__(512,1): empirically allows ~256-VGPR budget (R4: (256,1)
// gave 216) so all 112 weight regs fit with NO spills (1024-thr blocks pin
// 64 VGPRs and spill — R7/R8/R9). Lean-LDS layout: f16-packed contiguous
// slices, ~108 LDS reads/thread/eval vs R6's ~450.
#define NBATCH 32
#define LPATH  513
#define NWIN   32
#define LSIG   36
#define DSTR   136   // [dir] stride sD1/sD2 (f16) = 17 uint4: conflict-free
#define USTR   72    // [dir] stride sU (f16) = 9 uint4

typedef unsigned int u32;
typedef _Float16 h2 __attribute__((ext_vector_type(2)));

__device__ __forceinline__ u32 pkh(float a, float b){
  return __builtin_bit_cast(u32, __builtin_amdgcn_cvt_pkrtz(a, b));
}
__device__ __forceinline__ float dot2(u32 a, u32 b, float c){
#if __has_builtin(__builtin_amdgcn_fdot2)
  return __builtin_amdgcn_fdot2(__builtin_bit_cast(h2,a),
                                __builtin_bit_cast(h2,b), c, false);
#else
  h2 x = __builtin_bit_cast(h2,a), y = __builtin_bit_cast(h2,b);
  return c + (float)x[0]*(float)y[0] + (float)x[1]*(float)y[1];
#endif
}
__device__ __forceinline__ float tanh_fast(float x){
  float e = __expf(2.f*x);
  return 1.f - 2.f/(e+1.f);
}

extern "C" __global__ __launch_bounds__(512, 1)
void cde_kernel(const float* __restrict__ cv,
                const float* __restrict__ Wi1g, const float* __restrict__ bi1g,
                const float* __restrict__ Wi2g, const float* __restrict__ bi2g,
                const float* __restrict__ W1g,  const float* __restrict__ b1g,
                const float* __restrict__ W2g,  const float* __restrict__ b2g,
                const float* __restrict__ W3g,  const float* __restrict__ b3g,
                const float* __restrict__ Wrg,  const float* __restrict__ brg,
                const float* __restrict__ shg,
                float* __restrict__ outp)
{
  // ---- LDS (~17 KB) ----
  __shared__ float sG[NWIN*LSIG];
  __shared__ __align__(16) float sF[512];
  __shared__ float sCon[512];
  __shared__ float sB3[512];
  __shared__ float sB1[128], sB2[128];
  __shared__ __align__(16) float sWr[256];
  __shared__ float sBr[4], sSh[1];
  __shared__ float sC[64];
  __shared__ float sY[64], sK1[64], sLw[64];
  __shared__ __align__(16) _Float16 sYinp[64];
  __shared__ __align__(16) _Float16 sH1[128];
  __shared__ __align__(16) _Float16 sH2[128];
  __shared__ __align__(16) _Float16 sU [8*USTR];
  __shared__ __align__(16) _Float16 sD1[8*DSTR];
  __shared__ __align__(16) _Float16 sD2[8*DSTR];

  const int t  = threadIdx.x;        // 0..511
  const int b  = blockIdx.x;
  const int r  = t >> 2;             // 0..127 (ph1/2/4/5 row)
  const int m  = t & 1;              // col half
  const int g  = (t >> 1) & 1;       // dir group (4 dirs each)
  const int j6 = t >> 6;             // dir for ph3/6 row block (row = t)

  // ---- init biases / readout ----
  if (t < 512) sB3[t] = b3g[t];
  if (t < 128){ sB1[t] = b1g[t]; sB2[t] = b2g[t]; }
  if (t < 256) sWr[t] = Wrg[t];
  if (t < 4)   sBr[t] = brg[t];
  if (t == 0)  sSh[0] = shg[0];

  // ---- depth-2 Lyndon log-signatures, one window per thread (t<32) ----
  if (t < NWIN){
    const float4* cv4 = (const float4*)cv;
    const int base = (b*LPATH + t*16)*2;
    float cur[8], pre[8], acc[8], lv[28];
    { float4 a = cv4[base], d = cv4[base+1];
      cur[0]=a.x;cur[1]=a.y;cur[2]=a.z;cur[3]=a.w;
      cur[4]=d.x;cur[5]=d.y;cur[6]=d.z;cur[7]=d.w; }
    #pragma unroll
    for (int d=0; d<8; d++){ pre[d]=0.f; acc[d]=0.f; }
    #pragma unroll
    for (int p=0; p<28; p++) lv[p]=0.f;
    for (int w=1; w<=16; w++){
      float nxt[8], inc[8];
      { float4 a = cv4[base+2*w], d = cv4[base+2*w+1];
        nxt[0]=a.x;nxt[1]=a.y;nxt[2]=a.z;nxt[3]=a.w;
        nxt[4]=d.x;nxt[5]=d.y;nxt[6]=d.z;nxt[7]=d.w; }
      #pragma unroll
      for (int d=0; d<8; d++) inc[d] = nxt[d]-cur[d];
      int p=0;
      #pragma unroll
      for (int i=0; i<8; i++)
        #pragma unroll
        for (int j2=i+1; j2<8; j2++){ lv[p] += pre[i]*inc[j2] - pre[j2]*inc[i]; p++; }
      #pragma unroll
      for (int d=0; d<8; d++){ acc[d]+=inc[d]; pre[d]+=inc[d]; cur[d]=nxt[d]; }
    }
    float* gd = &sG[t*LSIG];
    #pragma unroll
    for (int d=0; d<8; d++) gd[d] = acc[d];
    #pragma unroll
    for (int p=0; p<28; p++) gd[8+p] = 0.5f*lv[p];
  }

  // ---- y0 = Wi2 @ lipswish(Wi1 @ x0 + bi1) + bi2 ----
  if (t < 64){
    float z = bi1g[t];
    #pragma unroll
    for (int d=0; d<8; d++) z += Wi1g[t*8+d] * cv[(b*LPATH)*8 + d];
    float s = 1.f/(1.f+__expf(-z));
    sLw[t] = 0.909f*z*s;
  }
  __syncthreads();
  if (t < 64){
    float z = bi2g[t];
    #pragma unroll 8
    for (int k=0; k<64; k++) z += Wi2g[t*64+k] * sLw[k];
    sY[t] = z;
    sYinp[t] = (_Float16)z;
  }
  __syncthreads();
  if (t < 4){
    float z = sBr[t] + sSh[0];
    #pragma unroll 8
    for (int a=0; a<64; a++) z += sWr[t*64+a]*sY[a];
    outp[(b*33 + 0)*4 + t] = z;
  }

  // ---- per-thread weight registers: 16 + 32 + 64 = 112 u32 (f16 pairs) ----
  u32 w1h[16], w2h[32], w3r[64];
  {
    const float2* W1f2 = (const float2*)W1g;
    #pragma unroll
    for (int i=0; i<16; i++){ float2 v = W1f2[r*32 + m*16 + i]; w1h[i] = pkh(v.x, v.y); }
    const float2* W2f2 = (const float2*)W2g;
    #pragma unroll
    for (int i=0; i<32; i++){ float2 v = W2f2[r*64 + m*32 + i]; w2h[i] = pkh(v.x, v.y); }
    const float4* W3f4 = (const float4*)W3g;
    #pragma unroll
    for (int k=0; k<32; k++){
      float4 v = W3f4[t*32 + k];
      w3r[2*k]   = pkh(v.x, v.y);
      w3r[2*k+1] = pkh(v.z, v.w);
    }
  }

  // One vector-field eval. mode 0: k1 (write sK1, sYinp=y+k1, fused sC +
  // readout in ph1 region). mode 1: k2 (Heun update fused in ph7).
  auto EVAL = [&](const float* gcur, int mode, int s){
    __syncthreads();                          // sYinp (and sY) ready
    float dp1, dp2, fr;
    // ph1 region: W1@y + fused sC-compute + fused readout of y_s
    {
      if (mode == 0){
        if (t < 64){                          // bracket coeffs C[j*8+i]
          int j = t >> 3, i = t & 7;
          float v = 0.f;
          if (i < j)      v =  gcur[8 + (7*i - (i*(i-1))/2 + (j-i-1))];
          else if (i > j) v = -gcur[8 + (7*j - (j*(j-1))/2 + (i-j-1))];
          sC[t] = v;
        }
        if (s > 0 && t >= 504 && t < 508){    // readout of incoming y_s
          int o = t - 504;
          float z = sBr[o] + sSh[0];
          const float4* wr4 = (const float4*)&sWr[o*64];
          const float4* y4f = (const float4*)sY;
          #pragma unroll
          for (int q=0; q<16; q++){
            float4 w = wr4[q], y = y4f[q];
            z += w.x*y.x + w.y*y.y + w.z*y.z + w.w*y.w;
          }
          outp[(b*33 + s)*4 + o] = z;
        }
      }
      const uint4* y4 = (const uint4*)sYinp;
      uint4 a = y4[m*4+0], bb = y4[m*4+1], cc = y4[m*4+2], dd = y4[m*4+3];
      float z0 = dot2(w1h[0], a.x, 0.f), z1 = dot2(w1h[1], a.y, 0.f);
      z0 = dot2(w1h[2],  a.z, z0);  z1 = dot2(w1h[3],  a.w, z1);
      z0 = dot2(w1h[4],  bb.x, z0); z1 = dot2(w1h[5],  bb.y, z1);
      z0 = dot2(w1h[6],  bb.z, z0); z1 = dot2(w1h[7],  bb.w, z1);
      z0 = dot2(w1h[8],  cc.x, z0); z1 = dot2(w1h[9],  cc.y, z1);
      z0 = dot2(w1h[10], cc.z, z0); z1 = dot2(w1h[11], cc.w, z1);
      z0 = dot2(w1h[12], dd.x, z0); z1 = dot2(w1h[13], dd.y, z1);
      z0 = dot2(w1h[14], dd.z, z0); z1 = dot2(w1h[15], dd.w, z1);
      float z = z0 + z1;
      z += __shfl_xor(z, 1);                  // sum col halves (m)
      z += sB1[r];
      float sg = 1.f/(1.f+__expf(-z));
      dp1 = 0.909f*sg*(1.f + z*(1.f-sg));
      if ((t & 3) == 0) sH1[r] = (_Float16)(0.909f*z*sg);
    }
    __syncthreads();
    // ph2: W2@h1. (r,m): 64-col half, 32 dot2, 1 shfl.
    {
      const uint4* h4 = (const uint4*)sH1;
      float z0 = 0.f, z1 = 0.f;
      #pragma unroll
      for (int q=0; q<8; q++){
        uint4 v = h4[m*8 + q];
        z0 = dot2(w2h[4*q+0], v.x, z0); z1 = dot2(w2h[4*q+1], v.y, z1);
        z0 = dot2(w2h[4*q+2], v.z, z0); z1 = dot2(w2h[4*q+3], v.w, z1);
      }
      float z = z0 + z1;
      z += __shfl_xor(z, 1);
      z += sB2[r];
      float sg = 1.f/(1.f+__expf(-z));
      dp2 = 0.909f*sg*(1.f + z*(1.f-sg));
      if ((t & 3) == 0) sH2[r] = (_Float16)(0.909f*z*sg);
    }
    __syncthreads();
    // ph3: f = tanh(W3@h2 + b3). Row t, full 128 cols in regs, 0 shfl.
    {
      const uint4* h4 = (const uint4*)sH2;    // wave-uniform broadcast reads
      float a0=0.f, a1=0.f, a2=0.f, a3=0.f;
      #pragma unroll
      for (int q=0; q<16; q++){
        uint4 hv = h4[q];
        a0 = dot2(w3r[4*q+0], hv.x, a0);
        a1 = dot2(w3r[4*q+1], hv.y, a1);
        a2 = dot2(w3r[4*q+2], hv.z, a2);
        a3 = dot2(w3r[4*q+3], hv.w, a3);
      }
      fr = tanh_fast((a0+a1)+(a2+a3) + sB3[t]);
      sF[t] = fr;
    }
    __syncthreads();
    // U-fold: u_j[bb] = sum_i C[j,i] f[i*64+bb]; 1:1, no dup.
    {
      int bb = t & 63;
      float u = 0.f;
      #pragma unroll
      for (int i=0; i<8; i++) u += sC[j6*8 + i] * sF[i*64 + bb];
      sU[j6*USTR + bb] = (_Float16)u;
    }
    __syncthreads();
    // ph4: D1[d] = dp1 * (W1 @ u_d). (r,m,g): 4 dirs x 32-col half.
    {
      const uint4* u4 = (const uint4*)sU;     // dir stride 9 uint4
      #pragma unroll
      for (int k=0; k<4; k++){
        int dir = 4*g + k;
        const uint4* ud = &u4[dir*9 + m*4];
        uint4 a = ud[0], bb = ud[1], cc = ud[2], dd = ud[3];
        float z0 = dot2(w1h[0], a.x, 0.f), z1 = dot2(w1h[1], a.y, 0.f);
        z0 = dot2(w1h[2],  a.z, z0);  z1 = dot2(w1h[3],  a.w, z1);
        z0 = dot2(w1h[4],  bb.x, z0); z1 = dot2(w1h[5],  bb.y, z1);
        z0 = dot2(w1h[6],  bb.z, z0); z1 = dot2(w1h[7],  bb.w, z1);
        z0 = dot2(w1h[8],  cc.x, z0); z1 = dot2(w1h[9],  cc.y, z1);
        z0 = dot2(w1h[10], cc.z, z0); z1 = dot2(w1h[11], cc.w, z1);
        z0 = dot2(w1h[12], dd.x, z0); z1 = dot2(w1h[13], dd.y, z1);
        z0 = dot2(w1h[14], dd.z, z0); z1 = dot2(w1h[15], dd.w, z1);
        float z = z0 + z1;
        z += __shfl_xor(z, 1);
        if (m == 0) sD1[dir*DSTR + r] = (_Float16)(dp1*z);
      }
    }
    __syncthreads();
    // ph5: D2[d] = dp2 * (W2 @ D1[d]). (r,m,g): 4 dirs x 64-col half.
    {
      const uint4* d4 = (const uint4*)sD1;    // dir stride 17 uint4
      #pragma unroll
      for (int k=0; k<4; k++){
        int dir = 4*g + k;
        const uint4* dd = &d4[dir*17 + m*8];
        float z0 = 0.f, z1 = 0.f;
        #pragma unroll
        for (int q=0; q<8; q++){
          uint4 v = dd[q];
          z0 = dot2(w2h[4*q+0], v.x, z0); z1 = dot2(w2h[4*q+1], v.y, z1);
          z0 = dot2(w2h[4*q+2], v.z, z0); z1 = dot2(w2h[4*q+3], v.w, z1);
        }
        float z = z0 + z1;
        z += __shfl_xor(z, 1);
        if (m == 0) sD2[dir*DSTR + r] = (_Float16)(dp2*z);
      }
    }
    __syncthreads();
    // ph6: T3[t] = W3[t]·D2[j6]; contribution. Row t, regs, 0 shfl.
    {
      const uint4* d4 = (const uint4*)&sD2[j6*DSTR];  // wave-uniform
      float a0=0.f, a1=0.f, a2=0.f, a3=0.f;
      #pragma unroll
      for (int q=0; q<16; q++){
        uint4 dv = d4[q];
        a0 = dot2(w3r[4*q+0], dv.x, a0);
        a1 = dot2(w3r[4*q+1], dv.y, a1);
        a2 = dot2(w3r[4*q+2], dv.z, a2);
        a3 = dot2(w3r[4*q+3], dv.w, a3);
      }
      float z = (a0+a1)+(a2+a3);
      sCon[t] = gcur[j6]*fr + (1.f - fr*fr)*z;
    }
    __syncthreads();
    // ph7: k[a] = sum_j contrib; fused Heun updates.
    if (t < 64){
      float k = 0.f;
      #pragma unroll
      for (int j=0; j<8; j++) k += sCon[j*64 + t];
      if (mode == 0){
        sK1[t] = k;
        sYinp[t] = (_Float16)(sY[t] + k);     // midpoint input for eval2
      } else {
        float yn = sY[t] + 0.5f*(sK1[t] + k);
        sY[t] = yn;
        sYinp[t] = (_Float16)yn;
      }
    }
  };

  // ---- main scan over windows ----
  for (int s = 0; s < NWIN; s++){
    const float* gcur = &sG[s*LSIG];
    EVAL(gcur, 0, s);
    EVAL(gcur, 1, s);
  }
  __syncthreads();
  if (t < 4){                                 // final readout (y after win 31)
    float z = sBr[t] + sSh[0];
    #pragma unroll 8
    for (int a=0; a<64; a++) z += sWr[t*64+a]*sY[a];
    outp[(b*33 + 32)*4 + t] = z;
  }
}

extern "C" void kernel_launch(void* const* d_in, const int* in_sizes, int n_in,
                              void* d_out, int out_size, void* d_ws, size_t ws_size,
                              hipStream_t stream) {
  cde_kernel<<<dim3(NBATCH), dim3(512), 0, stream>>>(
      (const float*)d_in[0],
      (const float*)d_in[1],  (const float*)d_in[2],
      (const float*)d_in[3],  (const float*)d_in[4],
      (const float*)d_in[5],  (const float*)d_in[6],
      (const float*)d_in[7],  (const float*)d_in[8],
      (const float*)d_in[9],  (const float*)d_in[10],
      (const float*)d_in[11], (const float*)d_in[12],
      (const float*)d_in[13],
      (float*)d_out);
}